// Round 5
// baseline (128.938 us; speedup 1.0000x reference)
//
#include <hip/hip_runtime.h>

typedef __bf16 bf16;
typedef __bf16 bf16x4 __attribute__((ext_vector_type(4)));
typedef __bf16 bf16x8 __attribute__((ext_vector_type(8)));
typedef float  f32x4  __attribute__((ext_vector_type(4)));
typedef unsigned int uint32;

#define BT 64

// ---- bf16 workspace layout (element offsets) ----
// Only data that must be reordered (or is consumed repeatedly by costco) is staged:
//   W2F: w2 per-mode MFMA-fragment order [m][dt][ks][lane][8]   (196608)
//   F1 : wfc1 fragment order, NKS=8                              (65536)
//   F2 : wfc2                                                    (256)
// emb/w1/b1/b2 are read RAW by build_q (fragment pattern = 8-consecutive-elem loads).
#define O_W2F 0
#define O_F1  196608
#define O_F2  262144
#define N_TOT 262400

#define BYTES_BF16 ((size_t)N_TOT*2)
#define OFF_FLOAT  BYTES_BF16              // f32: b1(256) b2(256) bfc1(256) bfc2(1)
#define OFF_FLAG   (OFF_FLOAT + 772*4)
#define OFF_IDX    (OFF_FLAG + 16)         // int32 idx (131072*3)
#define N_IDX      (131072*3)
#define OFF_Q      (OFF_IDX + (size_t)N_IDX*4)

// Q tables (bf16): Q_m[i][d], 6228 rows total -> 3.19 MB (L2-resident)
// b2 is folded into Q0 at build time.
#define QB0 0
#define QB1 (339*256)
#define QB2 (QB1 + 5825*256)

static __device__ __forceinline__ f32x4 mfma16(bf16x8 a, bf16x8 b, f32x4 c) {
    return __builtin_amdgcn_mfma_f32_16x16x32_bf16(a, b, c, 0, 0, 0);
}

// load 8 consecutive elements from a raw (fp32 or bf16) buffer as bf16x8
static __device__ __forceinline__ bf16x8 load8(const void* p, size_t off, bool fp32) {
    if (fp32) {
        const float4* q = (const float4*)((const float*)p + off);
        float4 a = q[0], b = q[1];
        bf16x8 o;
        o[0]=(bf16)a.x; o[1]=(bf16)a.y; o[2]=(bf16)a.z; o[3]=(bf16)a.w;
        o[4]=(bf16)b.x; o[5]=(bf16)b.y; o[6]=(bf16)b.z; o[7]=(bf16)b.w;
        return o;
    }
    return *(const bf16x8*)((const bf16*)p + off);
}

// ---- prep kernel. Blocks: [0,256) idx; 256 biases+flag+wfc2;
// [257,273) wfc1 fragment tiles; [273,289) w2 fragment tiles.
// All reorders staged through LDS -> global writes are LINEAR uint4 streams.
__global__ __launch_bounds__(256)
void convert_all(const void* __restrict__ w1r, const void* __restrict__ w2r,
                 const void* __restrict__ b1r, const void* __restrict__ b2r,
                 const void* __restrict__ f1r, const void* __restrict__ fc1br,
                 const void* __restrict__ f2r, const void* __restrict__ fc2br,
                 const void* __restrict__ idxr,
                 bf16* __restrict__ wsb, float* __restrict__ wsf,
                 int* __restrict__ flagp, int* __restrict__ idx32)
{
    __shared__ alignas(16) bf16 sT[12288];
    __shared__ int sF;
    const int tid = threadIdx.x;
    const int bid = blockIdx.x;
    if (tid == 0) sF = 0;
    __syncthreads();

    if (bid < 256) {
        // i64 probe: int64 index buffers (values < 2^31) have all-zero odd words
        if (((const uint32*)idxr)[tid * 2 + 1] != 0) atomicOr(&sF, 1);
        __syncthreads();
        const bool i64 = (sF == 0);
        #pragma unroll
        for (int it = 0; it < 6; ++it) {
            int k = bid * 1536 + it * 256 + tid;
            if (k < N_IDX) {
                long long v = i64 ? ((const long long*)idxr)[k]
                                  : (long long)((const int*)idxr)[k];
                int m = k - (k / 3) * 3;
                long long dim = (m == 0 ? 339 : (m == 1 ? 5825 : 64));
                v = v < 0 ? 0 : (v >= dim ? dim - 1 : v);
                idx32[k] = (int)v;
            }
        }
        return;
    }

    // fp32 probe: low 16 bits of word as bf16 with exp>126 impossible for |w1|<=0.37
    if (tid < 64) {
        uint32 e = (((const uint32*)w1r)[tid] >> 7) & 0xffu;
        if (e > 126u) atomicOr(&sF, 1);
    }
    __syncthreads();
    const bool fp32 = (sF != 0);

    if (bid == 256) {
        if (tid == 0) *flagp = fp32 ? 1 : 0;
        #pragma unroll
        for (int it = 0; it < 4; ++it) {
            int j = it * 256 + tid;
            if (j < 769) {
                const void* src; int off;
                if (j < 256)      { src = b1r;   off = j; }
                else if (j < 512) { src = b2r;   off = j - 256; }
                else if (j < 768) { src = fc1br; off = j - 512; }
                else              { src = fc2br; off = 0; }
                wsf[j] = fp32 ? ((const float*)src)[off] : (float)((const bf16*)src)[off];
            }
        }
        // wfc2 -> O_F2 (straight)
        wsb[O_F2 + tid] = fp32 ? (bf16)((const float*)f2r)[tid]
                               : ((const bf16*)f2r)[tid];
    } else if (bid < 273) {
        // wfc1 tile et: rows e in [et*16,(et+1)*16). 4096 elems.
        // linear read -> LDS fragment scatter -> linear 8KB write.
        const int et = bid - 257;
        #pragma unroll
        for (int it = 0; it < 4; ++it) {
            unsigned g = it * 1024u + tid * 4u;      // elem within tile
            unsigned goff = et * 4096u + g;          // elem within wfc1
            bf16 v4[4];
            if (fp32) {
                float4 t = *(const float4*)((const float*)f1r + goff);
                v4[0]=(bf16)t.x; v4[1]=(bf16)t.y; v4[2]=(bf16)t.z; v4[3]=(bf16)t.w;
            } else {
                bf16x4 t = *(const bf16x4*)((const bf16*)f1r + goff);
                v4[0]=t[0]; v4[1]=t[1]; v4[2]=t[2]; v4[3]=t[3];
            }
            #pragma unroll
            for (int q2 = 0; q2 < 4; ++q2) {
                unsigned e = goff + q2;
                unsigned ee = e >> 8, kk = e & 255u;
                unsigned slot = ((kk >> 5) * 64u + ((kk >> 3) & 3u) * 16u + (ee & 15u)) * 8u
                                + (kk & 7u);
                sT[slot] = v4[q2];
            }
        }
        __syncthreads();
        #pragma unroll
        for (int it = 0; it < 2; ++it)
            *(uint4*)(wsb + O_F1 + et * 4096 + it * 2048 + tid * 8) =
                *(const uint4*)(&sT[it * 2048 + tid * 8]);
    } else {
        // w2 tile dt: d in [dt*16,(dt+1)*16). 12288 source elems (all 3 modes).
        const int dt = bid - 273;
        #pragma unroll
        for (int it = 0; it < 12; ++it) {
            unsigned g = it * 1024u + tid * 4u;      // within 12288
            unsigned goff = dt * 12288u + g;
            bf16 v4[4];
            if (fp32) {
                float4 t = *(const float4*)((const float*)w2r + goff);
                v4[0]=(bf16)t.x; v4[1]=(bf16)t.y; v4[2]=(bf16)t.z; v4[3]=(bf16)t.w;
            } else {
                bf16x4 t = *(const bf16x4*)((const bf16*)w2r + goff);
                v4[0]=t[0]; v4[1]=t[1]; v4[2]=t[2]; v4[3]=t[3];
            }
            unsigned dloc = g / 768u, rem = g - dloc * 768u;
            #pragma unroll
            for (int q2 = 0; q2 < 4; ++q2) {
                unsigned rr = rem + q2;
                unsigned c = rr / 3u, mm = rr - c * 3u;
                unsigned slot = mm * 4096u
                              + ((c >> 5) * 64u + ((c >> 3) & 3u) * 16u + dloc) * 8u
                              + (c & 7u);
                sT[slot] = v4[q2];
            }
        }
        __syncthreads();
        #pragma unroll
        for (int it = 0; it < 6; ++it) {
            unsigned mm = it >> 1, h = it & 1;
            *(uint4*)(wsb + O_W2F + mm * 65536 + dt * 4096 + h * 2048 + tid * 8) =
                *(const uint4*)(&sT[mm * 4096 + h * 2048 + tid * 8]);
        }
    }
}

// ---- build Q tables: Q_m[i][d] = sum_c relu(<emb_m[i],w1[c]>+b1[c]) * w2[d][c][m]
// One 16-row tile per block -> 391 blocks. emb/w1/b1/b2 read RAW (fragment
// pattern = 8-consecutive-elem loads); w2 from staged W2F. b2 folded into Q0.
__global__ __launch_bounds__(256)
void build_q(const void* __restrict__ e0, const void* __restrict__ e1,
             const void* __restrict__ e2, const void* __restrict__ w1r,
             const void* __restrict__ b1r, const void* __restrict__ b2r,
             const bf16* __restrict__ wsb, bf16* __restrict__ Qt)
{
    __shared__ alignas(16) bf16 sPE[4096];
    __shared__ int sF;

    const int tid  = threadIdx.x;
    const int wave = tid >> 6;
    const int lane = tid & 63;
    const int quad = lane >> 4;
    const int l15  = lane & 15;
    const int bid  = blockIdx.x;

    if (tid == 0) sF = 0;
    __syncthreads();
    if (tid < 64) {
        uint32 e = (((const uint32*)w1r)[tid] >> 7) & 0xffu;
        if (e > 126u) atomicOr(&sF, 1);
    }
    __syncthreads();
    const bool fp32 = (sF != 0);

    int m, tile, dim, qBase;
    const void* eraw;
    if (bid < 22)       { m = 0; tile = bid;       dim = 339;  eraw = e0; qBase = QB0; }
    else if (bid < 387) { m = 1; tile = bid - 22;  dim = 5825; eraw = e1; qBase = QB1; }
    else                { m = 2; tile = bid - 387; dim = 64;   eraw = e2; qBase = QB2; }
    const int row0 = tile * 16;

    const bf16* w2f = wsb + O_W2F + m * 65536;
    const f32x4 zero4 = {0.f, 0.f, 0.f, 0.f};

    // emb B-fragments, raw rows (clamped)
    int r = row0 + l15; r = r >= dim ? dim - 1 : r;
    bf16x8 be[4];
    #pragma unroll
    for (int ks = 0; ks < 4; ++ks)
        be[ks] = load8(eraw, (size_t)r * 128 + ks * 32 + quad * 8, fp32);

    // Stage PE: H[c][row] = relu(w1.emb^T + b1); write in stage-Q A-fragment layout.
    #pragma unroll
    for (int mtl = 0; mtl < 4; ++mtl) {
        int mt = wave * 4 + mtl;
        f32x4 acc = zero4;
        #pragma unroll
        for (int ks = 0; ks < 4; ++ks) {
            bf16x8 aw = load8(w1r, (size_t)(mt * 16 + l15) * 128 + ks * 32 + quad * 8, fp32);
            acc = mfma16(aw, be[ks], acc);
        }
        float bv[4];
        if (fp32) {
            float4 t = *(const float4*)((const float*)b1r + mt * 16 + quad * 4);
            bv[0]=t.x; bv[1]=t.y; bv[2]=t.z; bv[3]=t.w;
        } else {
            bf16x4 t = *(const bf16x4*)((const bf16*)b1r + mt * 16 + quad * 4);
            bv[0]=(float)t[0]; bv[1]=(float)t[1]; bv[2]=(float)t[2]; bv[3]=(float)t[3];
        }
        bf16x4 hv;
        hv[0] = (bf16)fmaxf(acc[0] + bv[0], 0.f);
        hv[1] = (bf16)fmaxf(acc[1] + bv[1], 0.f);
        hv[2] = (bf16)fmaxf(acc[2] + bv[2], 0.f);
        hv[3] = (bf16)fmaxf(acc[3] + bv[3], 0.f);
        // element (row=l15, c=mt*16+quad*4+r) -> A-frag (ks=c>>5, quadq=(c>>3)&3, j=c&7)
        int ksq   = mt >> 1;
        int quadq = ((mt & 1) << 1) | (quad >> 1);
        int j0    = (quad & 1) * 4;
        *(bf16x4*)(&sPE[(ksq * 64 + quadq * 16 + l15) * 8 + j0]) = hv;
    }
    __syncthreads();

    // Stage Q: A = H (16 rows), B = W2F d-tiles (wave*4+nt). No relu.
    f32x4 acc2[4];
    #pragma unroll
    for (int nt = 0; nt < 4; ++nt) acc2[nt] = zero4;
    #pragma unroll
    for (int ks = 0; ks < 8; ++ks) {
        bf16x8 af = *(const bf16x8*)(&sPE[(ks * 64 + lane) * 8]);
        #pragma unroll
        for (int nt = 0; nt < 4; ++nt) {
            bf16x8 bw = *(const bf16x8*)(w2f + (size_t)(((wave * 4 + nt) * 8 + ks) * 64 + lane) * 8);
            acc2[nt] = mfma16(af, bw, acc2[nt]);
        }
    }
    #pragma unroll
    for (int nt = 0; nt < 4; ++nt) {
        int d = (wave * 4 + nt) * 16 + l15;
        float addb = 0.f;
        if (m == 0)
            addb = fp32 ? ((const float*)b2r)[d] : (float)((const bf16*)b2r)[d];
        #pragma unroll
        for (int rr = 0; rr < 4; ++rr) {
            int rl = quad * 4 + rr;
            if (row0 + rl < dim)
                Qt[qBase + (size_t)(row0 + rl) * 256 + d] = (bf16)(acc2[nt][rr] + addb);
        }
    }
}

// ---- main: h2 = relu(Q0'[i0]+Q1[i1]+Q2[i2]); h3 = relu(h2 Wfc1^T + bfc1);
// ---- out = relu(h3.wfc2 + bfc2). 64 rows/block, ~34 KB LDS, 4 blocks/CU.
// (unchanged from round 4)
__global__ __launch_bounds__(256, 4)
void costco_main(const bf16* __restrict__ wsb, const bf16* __restrict__ Qt,
                 const float* __restrict__ wsf, const int* __restrict__ flagp,
                 const int* __restrict__ idx32, void* __restrict__ out)
{
    __shared__ alignas(16) bf16 sH2[BT * 256];
    __shared__ float sPart[4][BT];

    const bf16* wf   = wsb + O_F1;   // fragment-ordered wfc1
    const bf16* wfc2 = wsb + O_F2;
    const float* fbc1 = wsf + 512;
    const float  bfc2v = wsf[768];
    const int fp32out = *flagp;

    const int tid  = threadIdx.x;
    const int wave = tid >> 6;
    const int lane = tid & 63;
    const int quad = lane >> 4;
    const int l15  = lane & 15;
    const int bbase = blockIdx.x * BT;

    // ---- gather: half-wave per row, idx loaded straight to registers ----
    {
        const int half  = lane >> 5;
        const int l31   = lane & 31;
        const int ksw   = l31 >> 2;
        const int quadw = l31 & 3;
        int i0[8], i1[8], i2[8];
        #pragma unroll
        for (int rp = 0; rp < 8; ++rp) {
            const int gb = (bbase + wave * 16 + rp * 2 + half) * 3;
            i0[rp] = idx32[gb];
            i1[rp] = idx32[gb + 1];
            i2[rp] = idx32[gb + 2];
        }
        #pragma unroll
        for (int rp = 0; rp < 8; ++rp) {
            bf16x8 a = *(const bf16x8*)(Qt + QB0 + (size_t)i0[rp] * 256 + l31 * 8);
            bf16x8 b = *(const bf16x8*)(Qt + QB1 + (size_t)i1[rp] * 256 + l31 * 8);
            bf16x8 c = *(const bf16x8*)(Qt + QB2 + (size_t)i2[rp] * 256 + l31 * 8);
            bf16x8 o;
            #pragma unroll
            for (int j = 0; j < 8; ++j)
                o[j] = (bf16)fmaxf((float)a[j] + (float)b[j] + (float)c[j], 0.f);
            const int l15r = rp * 2 + half;
            *(bf16x8*)(&sH2[((wave * 8 + ksw) * 64 + quadw * 16 + (l15r ^ ksw)) * 8]) = o;
        }
    }

    // hoist ks=0 wfc1 B-fragments above the barrier
    bf16x8 bfr0[4];
    #pragma unroll
    for (int nt = 0; nt < 4; ++nt)
        bfr0[nt] = *(const bf16x8*)(wf + ((size_t)((wave * 4 + nt) * 8) * 64 + lane) * 8);

    __syncthreads();

    const f32x4 zero4 = {0.f, 0.f, 0.f, 0.f};

    // Stage C: h3 = relu(h2 Wfc1^T + bfc1), waves split N(e).
    f32x4 acc3[4][4];
    #pragma unroll
    for (int i = 0; i < 4; ++i)
        #pragma unroll
        for (int j = 0; j < 4; ++j) acc3[i][j] = zero4;
    #pragma unroll
    for (int ks = 0; ks < 8; ++ks) {
        bf16x8 af[4], bfr[4];
        #pragma unroll
        for (int mt = 0; mt < 4; ++mt)
            af[mt] = *(const bf16x8*)(&sH2[((mt * 8 + ks) * 64 + quad * 16 + (l15 ^ ks)) * 8]);
        #pragma unroll
        for (int nt = 0; nt < 4; ++nt)
            bfr[nt] = (ks == 0) ? bfr0[nt]
                    : *(const bf16x8*)(wf + ((size_t)((wave * 4 + nt) * 8 + ks) * 64 + lane) * 8);
        #pragma unroll
        for (int mt = 0; mt < 4; ++mt)
            #pragma unroll
            for (int nt = 0; nt < 4; ++nt)
                acc3[mt][nt] = mfma16(af[mt], bfr[nt], acc3[mt][nt]);
    }

    // Stage D: per-wave partial into sPart, then one reduction pass.
    float wv[4], bc[4];
    #pragma unroll
    for (int nt = 0; nt < 4; ++nt) {
        int e = wave * 64 + nt * 16 + l15;
        wv[nt] = (float)wfc2[e];
        bc[nt] = fbc1[e];
    }
    #pragma unroll
    for (int mt = 0; mt < 4; ++mt)
        #pragma unroll
        for (int r = 0; r < 4; ++r) {
            float p = 0.f;
            #pragma unroll
            for (int nt = 0; nt < 4; ++nt)
                p += fmaxf(acc3[mt][nt][r] + bc[nt], 0.f) * wv[nt];
            p += __shfl_xor(p, 1, 64);
            p += __shfl_xor(p, 2, 64);
            p += __shfl_xor(p, 4, 64);
            p += __shfl_xor(p, 8, 64);
            if (l15 == 0) sPart[wave][mt * 16 + quad * 4 + r] = p;
        }
    __syncthreads();

    if (tid < BT) {
        float v = sPart[0][tid] + sPart[1][tid] + sPart[2][tid] + sPart[3][tid] + bfc2v;
        v = fmaxf(v, 0.f);
        if (fp32out) ((float*)out)[bbase + tid] = v;
        else         ((bf16*)out)[bbase + tid] = (bf16)v;
    }
}

extern "C" void kernel_launch(void* const* d_in, const int* in_sizes, int n_in,
                              void* d_out, int out_size, void* d_ws, size_t ws_size,
                              hipStream_t stream) {
    char* ws = (char*)d_ws;
    bf16*  wsb   = (bf16*)ws;
    float* wsf   = (float*)(ws + OFF_FLOAT);
    int*   flagp = (int*)(ws + OFF_FLAG);
    int*   idx32 = (int*)(ws + OFF_IDX);
    bf16*  Qt    = (bf16*)(ws + OFF_Q);

    hipLaunchKernelGGL(convert_all, dim3(289), dim3(256), 0, stream,
                       d_in[4] /*w1*/, d_in[6] /*w2*/, d_in[5] /*b1*/,
                       d_in[7] /*b2*/, d_in[8] /*wfc1*/, d_in[9] /*bfc1*/,
                       d_in[10] /*wfc2*/, d_in[11] /*bfc2*/, d_in[0] /*idx*/,
                       wsb, wsf, flagp, idx32);

    hipLaunchKernelGGL(build_q, dim3(391), dim3(256), 0, stream,
                       d_in[1], d_in[2], d_in[3], d_in[4], d_in[5], d_in[7],
                       wsb, Qt);

    const int B = 131072;
    hipLaunchKernelGGL(costco_main, dim3(B / BT), dim3(256), 0, stream,
                       wsb, Qt, wsf, flagp, idx32, d_out);
}

// Round 6
// 121.832 us; speedup vs baseline: 1.0583x; 1.0583x over previous
//
#include <hip/hip_runtime.h>

typedef __bf16 bf16;
typedef __bf16 bf16x4 __attribute__((ext_vector_type(4)));
typedef __bf16 bf16x8 __attribute__((ext_vector_type(8)));
typedef float  f32x4  __attribute__((ext_vector_type(4)));
typedef unsigned int uint32;

#define BT 128

// ---- bf16 workspace layout (element offsets) ----
// All build_q operands stored in MFMA-fragment order:
//   frag(ee,kk,NKS): (((ee>>4)*NKS + (kk>>5))*64 + ((kk>>3)&3)*16 + (ee&15))*8 + (kk&7)
// EF*: emb tables, 16-row tiles (2048 elems/tile), padded to tile count.
#define N_EF0 (22*2048)
#define N_EF1 (365*2048)
#define N_EF2 (4*2048)
#define O_EF0 0
#define O_EF1 (O_EF0+N_EF0)      // 45056
#define O_EF2 (O_EF1+N_EF1)      // 792576
#define O_W1F (O_EF2+N_EF2)      // 800768  w1 fragment order (NKS=4)
#define O_W2F (O_W1F+32768)      // 833536  w2 per-mode fragment order [m][dt][ks][lane][8]
#define O_F1  (O_W2F+196608)     // 1030144 wfc1 fragment order (NKS=8)
#define O_F2  (O_F1+65536)       // 1095680 wfc2
#define N_TOT (O_F2+256)         // 1095936 bf16

#define BYTES_BF16 ((size_t)N_TOT*2)
#define OFF_FLOAT  BYTES_BF16              // f32: b1(256) b2(256) bfc1(256) bfc2(1)
#define OFF_FLAG   (OFF_FLOAT + 772*4)
#define OFF_IDX    (OFF_FLAG + 16)         // int32 idx (131072*3)
#define N_IDX      (131072*3)
#define OFF_Q      (OFF_IDX + (size_t)N_IDX*4)

// Q tables (bf16): Q_m[i][d], 6228 rows total -> 3.19 MB (L2-resident)
// b2 is folded into Q0 at build time.
#define QB0 0
#define QB1 (339*256)
#define QB2 (QB1 + 5825*256)

static __device__ __forceinline__ f32x4 mfma16(bf16x8 a, bf16x8 b, f32x4 c) {
    return __builtin_amdgcn_mfma_f32_16x16x32_bf16(a, b, c, 0, 0, 0);
}

static __device__ __forceinline__ unsigned frag_off(unsigned ee, unsigned kk, unsigned nks) {
    return (((ee >> 4) * nks + (kk >> 5)) * 64u + ((kk >> 3) & 3u) * 16u + (ee & 15u)) * 8u
           + (kk & 7u);
}

// ---- normalization. Block ranges: [0,256) idx; [256,768) fragment-copy;
// [768,1008) w2 fragment-transpose; 1008 biases+flag. (R4-verified structure)
__global__ __launch_bounds__(256)
void convert_all(const void* __restrict__ e0, const void* __restrict__ e1,
                 const void* __restrict__ e2, const void* __restrict__ w1r,
                 const void* __restrict__ b1r, const void* __restrict__ w2r,
                 const void* __restrict__ b2r, const void* __restrict__ f1r,
                 const void* __restrict__ fc1br, const void* __restrict__ f2r,
                 const void* __restrict__ fc2br, const void* __restrict__ idxr,
                 bf16* __restrict__ wsb, float* __restrict__ wsf,
                 int* __restrict__ flagp, int* __restrict__ idx32)
{
    __shared__ int sF;
    const int tid = threadIdx.x;
    const int bid = blockIdx.x;
    if (tid == 0) sF = 0;
    __syncthreads();

    if (bid < 256) {
        // i64 probe: int64 index buffers (values < 2^31) have all-zero odd words
        if (((const uint32*)idxr)[tid * 2 + 1] != 0) atomicOr(&sF, 1);
        __syncthreads();
        const bool i64 = (sF == 0);
        #pragma unroll
        for (int it = 0; it < 6; ++it) {
            int k = bid * 1536 + it * 256 + tid;
            if (k < N_IDX) {
                long long v = i64 ? ((const long long*)idxr)[k]
                                  : (long long)((const int*)idxr)[k];
                int m = k - (k / 3) * 3;
                long long dim = (m == 0 ? 339 : (m == 1 ? 5825 : 64));
                v = v < 0 ? 0 : (v >= dim ? dim - 1 : v);
                idx32[k] = (int)v;
            }
        }
        return;
    }

    // fp32 probe: low 16 bits of word as bf16 with exp>126 impossible for |w1|<=0.37
    if (tid < 64) {
        uint32 e = (((const uint32*)w1r)[tid] >> 7) & 0xffu;
        if (e > 126u) atomicOr(&sF, 1);
    }
    __syncthreads();
    const bool fp32 = (sF != 0);

    if (bid < 768) {
        // fragment-copy, source-linear in 4-elt chunks (all region sizes %4==0).
        // cum: e0 43392 | e1 788992 | e2 797184 | w1 829952 | f1 895488 | f2 895744
        const unsigned n4 = 895744u / 4u;
        for (unsigned u = (bid - 256) * 256u + tid; u < n4; u += 512u * 256u) {
            unsigned e = u * 4;
            const void* src; unsigned off, dst;
            if (e < 829952u) {   // emb/w1: fragment NKS=4
                unsigned base;
                if (e < 43392u)       { src = e0;  off = e;           base = O_EF0; }
                else if (e < 788992u) { src = e1;  off = e - 43392u;  base = O_EF1; }
                else if (e < 797184u) { src = e2;  off = e - 788992u; base = O_EF2; }
                else                  { src = w1r; off = e - 797184u; base = O_W1F; }
                dst = base + frag_off(off >> 7, off & 127u, 4u);
            } else if (e < 895488u) {  // wfc1: fragment NKS=8
                src = f1r; off = e - 829952u;
                dst = O_F1 + frag_off(off >> 8, off & 255u, 8u);
            } else {                   // wfc2 straight
                src = f2r; off = e - 895488u; dst = O_F2 + off;
            }
            if (fp32) {
                float4 v = *(const float4*)((const float*)src + off);
                bf16x4 o; o[0]=(bf16)v.x; o[1]=(bf16)v.y; o[2]=(bf16)v.z; o[3]=(bf16)v.w;
                *(bf16x4*)(wsb + dst) = o;
            } else {
                *(uint2*)(wsb + dst) = *(const uint2*)((const bf16*)src + off);
            }
        }
    } else if (bid < 1008) {
        // W2F[m][dt][ks][lane][j] = w2[d][c][m], d=dt*16+(lane&15), c=ks*32+(lane>>4)*8+j
        for (unsigned i = (bid - 768) * 256u + tid; i < 196608u; i += 240u * 256u) {
            unsigned m = i >> 16, r = i & 65535u;
            unsigned dt = r >> 12, ks = (r >> 9) & 7u, lane = (r >> 3) & 63u, j = r & 7u;
            unsigned d = dt * 16u + (lane & 15u);
            unsigned c = ks * 32u + (lane >> 4) * 8u + j;
            unsigned off = d * 768u + c * 3u + m;
            wsb[O_W2F + i] = fp32 ? (bf16)((const float*)w2r)[off] : ((const bf16*)w2r)[off];
        }
    } else {
        if (tid == 0) *flagp = fp32 ? 1 : 0;
        #pragma unroll
        for (int it = 0; it < 4; ++it) {
            int j = it * 256 + tid;
            if (j < 769) {
                const void* src; int off;
                if (j < 256)      { src = b1r;   off = j; }
                else if (j < 512) { src = b2r;   off = j - 256; }
                else if (j < 768) { src = fc1br; off = j - 512; }
                else              { src = fc2br; off = 0; }
                wsf[j] = fp32 ? ((const float*)src)[off] : (float)((const bf16*)src)[off];
            }
        }
    }
}

// ---- build Q tables: Q_m[i][d] = sum_c relu(<emb_m[i],w1[c]>+b1[c]) * w2[d][c][m]
// One 16-row tile per block -> 391 blocks. All global loads lane-linear.
// b2[d] folded into Q0 (mode 0). (R4-verified structure)
__global__ __launch_bounds__(256)
void build_q(const bf16* __restrict__ wsb, const float* __restrict__ wsf,
             bf16* __restrict__ Qt)
{
    __shared__ alignas(16) bf16 sPE[4096];

    const int tid  = threadIdx.x;
    const int wave = tid >> 6;
    const int lane = tid & 63;
    const int quad = lane >> 4;
    const int l15  = lane & 15;
    const int bid  = blockIdx.x;

    int m, tile, dim, efBase, qBase;
    if (bid < 22)       { m = 0; tile = bid;       dim = 339;  efBase = O_EF0; qBase = QB0; }
    else if (bid < 387) { m = 1; tile = bid - 22;  dim = 5825; efBase = O_EF1; qBase = QB1; }
    else                { m = 2; tile = bid - 387; dim = 64;   efBase = O_EF2; qBase = QB2; }
    const int row0 = tile * 16;

    const bf16* w1f = wsb + O_W1F;
    const bf16* w2f = wsb + O_W2F + m * 65536;
    const float* fb1 = wsf;
    const float* fb2 = wsf + 256;
    const f32x4 zero4 = {0.f, 0.f, 0.f, 0.f};

    // emb B-fragments for this tile (shared across all mt)
    bf16x8 be[4];
    #pragma unroll
    for (int ks = 0; ks < 4; ++ks)
        be[ks] = *(const bf16x8*)(wsb + efBase + (size_t)((tile * 4 + ks) * 64 + lane) * 8);

    // Stage PE: H[c][row] = relu(w1.emb^T + b1); write into stage-Q A-fragment layout.
    #pragma unroll
    for (int mtl = 0; mtl < 4; ++mtl) {
        int mt = wave * 4 + mtl;
        f32x4 acc = zero4;
        #pragma unroll
        for (int ks = 0; ks < 4; ++ks) {
            bf16x8 aw = *(const bf16x8*)(w1f + ((mt * 4 + ks) * 64 + lane) * 8);
            acc = mfma16(aw, be[ks], acc);
        }
        const float4 bv = *(const float4*)(fb1 + mt * 16 + quad * 4);
        bf16x4 hv;
        hv[0] = (bf16)fmaxf(acc[0] + bv.x, 0.f);
        hv[1] = (bf16)fmaxf(acc[1] + bv.y, 0.f);
        hv[2] = (bf16)fmaxf(acc[2] + bv.z, 0.f);
        hv[3] = (bf16)fmaxf(acc[3] + bv.w, 0.f);
        // element (row=l15, c=mt*16+quad*4+r) -> A-frag (ks=c>>5, quadq=(c>>3)&3, j=c&7)
        int ksq   = mt >> 1;
        int quadq = ((mt & 1) << 1) | (quad >> 1);
        int j0    = (quad & 1) * 4;
        *(bf16x4*)(&sPE[(ksq * 64 + quadq * 16 + l15) * 8 + j0]) = hv;
    }
    __syncthreads();

    // Stage Q: A = H (16 rows), B = W2F d-tiles (wave*4+nt). No relu.
    f32x4 acc2[4];
    #pragma unroll
    for (int nt = 0; nt < 4; ++nt) acc2[nt] = zero4;
    #pragma unroll
    for (int ks = 0; ks < 8; ++ks) {
        bf16x8 af = *(const bf16x8*)(&sPE[(ks * 64 + lane) * 8]);
        #pragma unroll
        for (int nt = 0; nt < 4; ++nt) {
            bf16x8 bw = *(const bf16x8*)(w2f + (size_t)(((wave * 4 + nt) * 8 + ks) * 64 + lane) * 8);
            acc2[nt] = mfma16(af, bw, acc2[nt]);
        }
    }
    #pragma unroll
    for (int nt = 0; nt < 4; ++nt) {
        int d = (wave * 4 + nt) * 16 + l15;
        const float addb = (m == 0) ? fb2[d] : 0.f;   // fold b2 into Q0
        #pragma unroll
        for (int r = 0; r < 4; ++r) {
            int rl = quad * 4 + r;
            if (row0 + rl < dim)
                Qt[qBase + (size_t)(row0 + rl) * 256 + d] = (bf16)(acc2[nt][r] + addb);
        }
    }
}

// ---- main: h2 = relu(Q0'[i0]+Q1[i1]+Q2[i2]); h3 = relu(h2 Wfc1^T + bfc1);
// ---- out = relu(h3.wfc2 + bfc2). BT=128 rows/block, 512 threads (8 waves),
// 68 KB LDS -> 2 blocks/CU (16 waves/CU). Halves per-row wfc1 L2 traffic vs BT=64.
// sH2 in XOR-swizzled MFMA-A-fragment order: chunk(mt,ks,quad,row)=
// (mt*8+ks)*64+quad*16+(row^ks), 16B chunks -> conflict-free stage-C reads.
__global__ __launch_bounds__(512, 4)
void costco_main(const bf16* __restrict__ wsb, const bf16* __restrict__ Qt,
                 const float* __restrict__ wsf, const int* __restrict__ flagp,
                 const int* __restrict__ idx32, void* __restrict__ out)
{
    __shared__ alignas(16) bf16 sH2[BT * 256];
    __shared__ float sPart[8][BT];

    const bf16* wf   = wsb + O_F1;   // fragment-ordered wfc1
    const bf16* wfc2 = wsb + O_F2;
    const float* fbc1 = wsf + 512;
    const float  bfc2v = wsf[768];
    const int fp32out = *flagp;

    const int tid  = threadIdx.x;
    const int wave = tid >> 6;        // 0..7
    const int lane = tid & 63;
    const int quad = lane >> 4;
    const int l15  = lane & 15;
    const int bbase = blockIdx.x * BT;

    // ---- gather: half-wave per row, 16 rows per wave, idx straight to regs ----
    {
        const int half  = lane >> 5;
        const int l31   = lane & 31;
        const int ksw   = l31 >> 2;
        const int quadw = l31 & 3;
        int i0[8], i1[8], i2[8];
        #pragma unroll
        for (int rp = 0; rp < 8; ++rp) {
            const int gb = (bbase + wave * 16 + rp * 2 + half) * 3;
            i0[rp] = idx32[gb];
            i1[rp] = idx32[gb + 1];
            i2[rp] = idx32[gb + 2];
        }
        #pragma unroll
        for (int rp = 0; rp < 8; ++rp) {
            bf16x8 a = *(const bf16x8*)(Qt + QB0 + (size_t)i0[rp] * 256 + l31 * 8);
            bf16x8 b = *(const bf16x8*)(Qt + QB1 + (size_t)i1[rp] * 256 + l31 * 8);
            bf16x8 c = *(const bf16x8*)(Qt + QB2 + (size_t)i2[rp] * 256 + l31 * 8);
            bf16x8 o;
            #pragma unroll
            for (int j = 0; j < 8; ++j)
                o[j] = (bf16)fmaxf((float)a[j] + (float)b[j] + (float)c[j], 0.f);
            const int l15r = rp * 2 + half;
            *(bf16x8*)(&sH2[((wave * 8 + ksw) * 64 + quadw * 16 + (l15r ^ ksw)) * 8]) = o;
        }
    }

    // hoist ks=0 wfc1 B-fragments above the barrier (L2 latency hides in drain)
    bf16x8 bfr0[2];
    #pragma unroll
    for (int nt = 0; nt < 2; ++nt)
        bfr0[nt] = *(const bf16x8*)(wf + ((size_t)((wave * 2 + nt) * 8) * 64 + lane) * 8);

    __syncthreads();

    const f32x4 zero4 = {0.f, 0.f, 0.f, 0.f};

    // Stage C: h3 = relu(h2 Wfc1^T + bfc1). 8 waves split N(e) into 8x32;
    // each wave: 8 row-tiles (mt) x 2 e-tiles (nt).
    f32x4 acc3[8][2];
    #pragma unroll
    for (int i = 0; i < 8; ++i)
        #pragma unroll
        for (int j = 0; j < 2; ++j) acc3[i][j] = zero4;
    #pragma unroll
    for (int ks = 0; ks < 8; ++ks) {
        bf16x8 bfr[2];
        #pragma unroll
        for (int nt = 0; nt < 2; ++nt)
            bfr[nt] = (ks == 0) ? bfr0[nt]
                    : *(const bf16x8*)(wf + ((size_t)((wave * 2 + nt) * 8 + ks) * 64 + lane) * 8);
        #pragma unroll
        for (int mt = 0; mt < 8; ++mt) {
            bf16x8 af = *(const bf16x8*)(&sH2[((mt * 8 + ks) * 64 + quad * 16 + (l15 ^ ks)) * 8]);
            #pragma unroll
            for (int nt = 0; nt < 2; ++nt)
                acc3[mt][nt] = mfma16(af, bfr[nt], acc3[mt][nt]);
        }
    }

    // Stage D: per-wave partial into sPart, then one reduction pass.
    float wv[2], bc[2];
    #pragma unroll
    for (int nt = 0; nt < 2; ++nt) {
        int e = (wave * 2 + nt) * 16 + l15;
        wv[nt] = (float)wfc2[e];
        bc[nt] = fbc1[e];
    }
    #pragma unroll
    for (int mt = 0; mt < 8; ++mt)
        #pragma unroll
        for (int r = 0; r < 4; ++r) {
            float p = 0.f;
            #pragma unroll
            for (int nt = 0; nt < 2; ++nt)
                p += fmaxf(acc3[mt][nt][r] + bc[nt], 0.f) * wv[nt];
            p += __shfl_xor(p, 1, 64);
            p += __shfl_xor(p, 2, 64);
            p += __shfl_xor(p, 4, 64);
            p += __shfl_xor(p, 8, 64);
            if (l15 == 0) sPart[wave][mt * 16 + quad * 4 + r] = p;
        }
    __syncthreads();

    if (tid < BT) {
        float v = bfc2v;
        #pragma unroll
        for (int w = 0; w < 8; ++w) v += sPart[w][tid];
        v = fmaxf(v, 0.f);
        if (fp32out) ((float*)out)[bbase + tid] = v;
        else         ((bf16*)out)[bbase + tid] = (bf16)v;
    }
}

extern "C" void kernel_launch(void* const* d_in, const int* in_sizes, int n_in,
                              void* d_out, int out_size, void* d_ws, size_t ws_size,
                              hipStream_t stream) {
    char* ws = (char*)d_ws;
    bf16*  wsb   = (bf16*)ws;
    float* wsf   = (float*)(ws + OFF_FLOAT);
    int*   flagp = (int*)(ws + OFF_FLAG);
    int*   idx32 = (int*)(ws + OFF_IDX);
    bf16*  Qt    = (bf16*)(ws + OFF_Q);

    hipLaunchKernelGGL(convert_all, dim3(1009), dim3(256), 0, stream,
                       d_in[1], d_in[2], d_in[3], d_in[4], d_in[5], d_in[6],
                       d_in[7], d_in[8], d_in[9], d_in[10], d_in[11], d_in[0],
                       wsb, wsf, flagp, idx32);

    hipLaunchKernelGGL(build_q, dim3(391), dim3(256), 0, stream, wsb, wsf, Qt);

    const int B = 131072;
    hipLaunchKernelGGL(costco_main, dim3(B / BT), dim3(512), 0, stream,
                       wsb, Qt, wsf, flagp, idx32, d_out);
}

// Round 7
// 121.739 us; speedup vs baseline: 1.0591x; 1.0008x over previous
//
#include <hip/hip_runtime.h>

typedef __bf16 bf16;
typedef __bf16 bf16x4 __attribute__((ext_vector_type(4)));
typedef __bf16 bf16x8 __attribute__((ext_vector_type(8)));
typedef float  f32x4  __attribute__((ext_vector_type(4)));
typedef unsigned int uint32;

#define BT 32

// ---- bf16 workspace layout (element offsets) ----
// All build_q operands stored in MFMA-fragment order:
//   frag(ee,kk,NKS): (((ee>>4)*NKS + (kk>>5))*64 + ((kk>>3)&3)*16 + (ee&15))*8 + (kk&7)
// EF*: emb tables, 16-row tiles (2048 elems/tile), padded to tile count.
#define N_EF0 (22*2048)
#define N_EF1 (365*2048)
#define N_EF2 (4*2048)
#define O_EF0 0
#define O_EF1 (O_EF0+N_EF0)      // 45056
#define O_EF2 (O_EF1+N_EF1)      // 792576
#define O_W1F (O_EF2+N_EF2)      // 800768  w1 fragment order (NKS=4)
#define O_W2F (O_W1F+32768)      // 833536  w2 per-mode fragment order [m][dt][ks][lane][8]
#define O_F1  (O_W2F+196608)     // 1030144 wfc1 fragment order (NKS=8)
#define O_F2  (O_F1+65536)       // 1095680 wfc2
#define N_TOT (O_F2+256)         // 1095936 bf16

#define BYTES_BF16 ((size_t)N_TOT*2)
#define OFF_FLOAT  BYTES_BF16              // f32: b1(256) b2(256) bfc1(256) bfc2(1)
#define OFF_FLAG   (OFF_FLOAT + 772*4)
#define OFF_IDX    (OFF_FLAG + 16)         // int32 idx (131072*3)
#define N_IDX      (131072*3)
#define OFF_Q      (OFF_IDX + (size_t)N_IDX*4)

// Q tables (bf16): Q_m[i][d], 6228 rows total -> 3.19 MB (L2-resident)
// b2 is folded into Q0 at build time.
#define QB0 0
#define QB1 (339*256)
#define QB2 (QB1 + 5825*256)

static __device__ __forceinline__ f32x4 mfma16(bf16x8 a, bf16x8 b, f32x4 c) {
    return __builtin_amdgcn_mfma_f32_16x16x32_bf16(a, b, c, 0, 0, 0);
}

static __device__ __forceinline__ unsigned frag_off(unsigned ee, unsigned kk, unsigned nks) {
    return (((ee >> 4) * nks + (kk >> 5)) * 64u + ((kk >> 3) & 3u) * 16u + (ee & 15u)) * 8u
           + (kk & 7u);
}

// ---- normalization. Block ranges: [0,256) idx; [256,768) fragment-copy;
// [768,1008) w2 fragment-transpose; 1008 biases+flag. (R4-verified structure)
__global__ __launch_bounds__(256)
void convert_all(const void* __restrict__ e0, const void* __restrict__ e1,
                 const void* __restrict__ e2, const void* __restrict__ w1r,
                 const void* __restrict__ b1r, const void* __restrict__ w2r,
                 const void* __restrict__ b2r, const void* __restrict__ f1r,
                 const void* __restrict__ fc1br, const void* __restrict__ f2r,
                 const void* __restrict__ fc2br, const void* __restrict__ idxr,
                 bf16* __restrict__ wsb, float* __restrict__ wsf,
                 int* __restrict__ flagp, int* __restrict__ idx32)
{
    __shared__ int sF;
    const int tid = threadIdx.x;
    const int bid = blockIdx.x;
    if (tid == 0) sF = 0;
    __syncthreads();

    if (bid < 256) {
        // i64 probe: int64 index buffers (values < 2^31) have all-zero odd words
        if (((const uint32*)idxr)[tid * 2 + 1] != 0) atomicOr(&sF, 1);
        __syncthreads();
        const bool i64 = (sF == 0);
        #pragma unroll
        for (int it = 0; it < 6; ++it) {
            int k = bid * 1536 + it * 256 + tid;
            if (k < N_IDX) {
                long long v = i64 ? ((const long long*)idxr)[k]
                                  : (long long)((const int*)idxr)[k];
                int m = k - (k / 3) * 3;
                long long dim = (m == 0 ? 339 : (m == 1 ? 5825 : 64));
                v = v < 0 ? 0 : (v >= dim ? dim - 1 : v);
                idx32[k] = (int)v;
            }
        }
        return;
    }

    // fp32 probe: low 16 bits of word as bf16 with exp>126 impossible for |w1|<=0.37
    if (tid < 64) {
        uint32 e = (((const uint32*)w1r)[tid] >> 7) & 0xffu;
        if (e > 126u) atomicOr(&sF, 1);
    }
    __syncthreads();
    const bool fp32 = (sF != 0);

    if (bid < 768) {
        // fragment-copy, source-linear in 4-elt chunks (all region sizes %4==0).
        // cum: e0 43392 | e1 788992 | e2 797184 | w1 829952 | f1 895488 | f2 895744
        const unsigned n4 = 895744u / 4u;
        for (unsigned u = (bid - 256) * 256u + tid; u < n4; u += 512u * 256u) {
            unsigned e = u * 4;
            const void* src; unsigned off, dst;
            if (e < 829952u) {   // emb/w1: fragment NKS=4
                unsigned base;
                if (e < 43392u)       { src = e0;  off = e;           base = O_EF0; }
                else if (e < 788992u) { src = e1;  off = e - 43392u;  base = O_EF1; }
                else if (e < 797184u) { src = e2;  off = e - 788992u; base = O_EF2; }
                else                  { src = w1r; off = e - 797184u; base = O_W1F; }
                dst = base + frag_off(off >> 7, off & 127u, 4u);
            } else if (e < 895488u) {  // wfc1: fragment NKS=8
                src = f1r; off = e - 829952u;
                dst = O_F1 + frag_off(off >> 8, off & 255u, 8u);
            } else {                   // wfc2 straight
                src = f2r; off = e - 895488u; dst = O_F2 + off;
            }
            if (fp32) {
                float4 v = *(const float4*)((const float*)src + off);
                bf16x4 o; o[0]=(bf16)v.x; o[1]=(bf16)v.y; o[2]=(bf16)v.z; o[3]=(bf16)v.w;
                *(bf16x4*)(wsb + dst) = o;
            } else {
                *(uint2*)(wsb + dst) = *(const uint2*)((const bf16*)src + off);
            }
        }
    } else if (bid < 1008) {
        // W2F[m][dt][ks][lane][j] = w2[d][c][m], d=dt*16+(lane&15), c=ks*32+(lane>>4)*8+j
        for (unsigned i = (bid - 768) * 256u + tid; i < 196608u; i += 240u * 256u) {
            unsigned m = i >> 16, r = i & 65535u;
            unsigned dt = r >> 12, ks = (r >> 9) & 7u, lane = (r >> 3) & 63u, j = r & 7u;
            unsigned d = dt * 16u + (lane & 15u);
            unsigned c = ks * 32u + (lane >> 4) * 8u + j;
            unsigned off = d * 768u + c * 3u + m;
            wsb[O_W2F + i] = fp32 ? (bf16)((const float*)w2r)[off] : ((const bf16*)w2r)[off];
        }
    } else {
        if (tid == 0) *flagp = fp32 ? 1 : 0;
        #pragma unroll
        for (int it = 0; it < 4; ++it) {
            int j = it * 256 + tid;
            if (j < 769) {
                const void* src; int off;
                if (j < 256)      { src = b1r;   off = j; }
                else if (j < 512) { src = b2r;   off = j - 256; }
                else if (j < 768) { src = fc1br; off = j - 512; }
                else              { src = fc2br; off = 0; }
                wsf[j] = fp32 ? ((const float*)src)[off] : (float)((const bf16*)src)[off];
            }
        }
    }
}

// ---- build Q tables: Q_m[i][d] = sum_c relu(<emb_m[i],w1[c]>+b1[c]) * w2[d][c][m]
// One 16-row tile per block -> 391 blocks. All global loads lane-linear.
// b2[d] folded into Q0 (mode 0). (R4-verified structure)
__global__ __launch_bounds__(256)
void build_q(const bf16* __restrict__ wsb, const float* __restrict__ wsf,
             bf16* __restrict__ Qt)
{
    __shared__ alignas(16) bf16 sPE[4096];

    const int tid  = threadIdx.x;
    const int wave = tid >> 6;
    const int lane = tid & 63;
    const int quad = lane >> 4;
    const int l15  = lane & 15;
    const int bid  = blockIdx.x;

    int m, tile, dim, efBase, qBase;
    if (bid < 22)       { m = 0; tile = bid;       dim = 339;  efBase = O_EF0; qBase = QB0; }
    else if (bid < 387) { m = 1; tile = bid - 22;  dim = 5825; efBase = O_EF1; qBase = QB1; }
    else                { m = 2; tile = bid - 387; dim = 64;   efBase = O_EF2; qBase = QB2; }
    const int row0 = tile * 16;

    const bf16* w1f = wsb + O_W1F;
    const bf16* w2f = wsb + O_W2F + m * 65536;
    const float* fb1 = wsf;
    const float* fb2 = wsf + 256;
    const f32x4 zero4 = {0.f, 0.f, 0.f, 0.f};

    // emb B-fragments for this tile (shared across all mt)
    bf16x8 be[4];
    #pragma unroll
    for (int ks = 0; ks < 4; ++ks)
        be[ks] = *(const bf16x8*)(wsb + efBase + (size_t)((tile * 4 + ks) * 64 + lane) * 8);

    // Stage PE: H[c][row] = relu(w1.emb^T + b1); write into stage-Q A-fragment layout.
    #pragma unroll
    for (int mtl = 0; mtl < 4; ++mtl) {
        int mt = wave * 4 + mtl;
        f32x4 acc = zero4;
        #pragma unroll
        for (int ks = 0; ks < 4; ++ks) {
            bf16x8 aw = *(const bf16x8*)(w1f + ((mt * 4 + ks) * 64 + lane) * 8);
            acc = mfma16(aw, be[ks], acc);
        }
        const float4 bv = *(const float4*)(fb1 + mt * 16 + quad * 4);
        bf16x4 hv;
        hv[0] = (bf16)fmaxf(acc[0] + bv.x, 0.f);
        hv[1] = (bf16)fmaxf(acc[1] + bv.y, 0.f);
        hv[2] = (bf16)fmaxf(acc[2] + bv.z, 0.f);
        hv[3] = (bf16)fmaxf(acc[3] + bv.w, 0.f);
        // element (row=l15, c=mt*16+quad*4+r) -> A-frag (ks=c>>5, quadq=(c>>3)&3, j=c&7)
        int ksq   = mt >> 1;
        int quadq = ((mt & 1) << 1) | (quad >> 1);
        int j0    = (quad & 1) * 4;
        *(bf16x4*)(&sPE[(ksq * 64 + quadq * 16 + l15) * 8 + j0]) = hv;
    }
    __syncthreads();

    // Stage Q: A = H (16 rows), B = W2F d-tiles (wave*4+nt). No relu.
    f32x4 acc2[4];
    #pragma unroll
    for (int nt = 0; nt < 4; ++nt) acc2[nt] = zero4;
    #pragma unroll
    for (int ks = 0; ks < 8; ++ks) {
        bf16x8 af = *(const bf16x8*)(&sPE[(ks * 64 + lane) * 8]);
        #pragma unroll
        for (int nt = 0; nt < 4; ++nt) {
            bf16x8 bw = *(const bf16x8*)(w2f + (size_t)(((wave * 4 + nt) * 8 + ks) * 64 + lane) * 8);
            acc2[nt] = mfma16(af, bw, acc2[nt]);
        }
    }
    #pragma unroll
    for (int nt = 0; nt < 4; ++nt) {
        int d = (wave * 4 + nt) * 16 + l15;
        const float addb = (m == 0) ? fb2[d] : 0.f;   // fold b2 into Q0
        #pragma unroll
        for (int r = 0; r < 4; ++r) {
            int rl = quad * 4 + r;
            if (row0 + rl < dim)
                Qt[qBase + (size_t)(row0 + rl) * 256 + d] = (bf16)(acc2[nt][r] + addb);
        }
    }
}

// ---- main: h2 = relu(Q0'[i0]+Q1[i1]+Q2[i2]); h3 = relu(h2 Wfc1^T + bfc1);
// ---- out = relu(h3.wfc2 + bfc2). BT=32 rows/block, 4096 blocks, ~17 KB LDS,
// 6 blocks/CU (24 waves/CU, launch_bounds VGPR<=85). Gather: half-wave per row,
// all 12 Q loads batched before consumption (12-deep MLP). sH2 XOR-swizzled
// A-fragment order: chunk(mt,ks,quad,row)= (mt*8+ks)*64+quad*16+(row^ks).
__global__ __launch_bounds__(256, 6)
void costco_main(const bf16* __restrict__ wsb, const bf16* __restrict__ Qt,
                 const float* __restrict__ wsf, const int* __restrict__ flagp,
                 const int* __restrict__ idx32, void* __restrict__ out)
{
    __shared__ alignas(16) bf16 sH2[BT * 256];
    __shared__ float sPart[4][BT];

    const bf16* wf   = wsb + O_F1;   // fragment-ordered wfc1
    const bf16* wfc2 = wsb + O_F2;
    const float* fbc1 = wsf + 512;
    const float  bfc2v = wsf[768];
    const int fp32out = *flagp;

    const int tid  = threadIdx.x;
    const int wave = tid >> 6;
    const int lane = tid & 63;
    const int quad = lane >> 4;
    const int l15  = lane & 15;
    const int bbase = blockIdx.x * BT;

    // ---- gather: half-wave per row, 8 rows per wave, fully batched loads ----
    {
        const int half  = lane >> 5;
        const int l31   = lane & 31;
        const int ksw   = l31 >> 2;
        const int quadw = l31 & 3;
        int i0[4], i1[4], i2[4];
        #pragma unroll
        for (int rp = 0; rp < 4; ++rp) {
            const int gb = (bbase + wave * 8 + rp * 2 + half) * 3;
            i0[rp] = idx32[gb];
            i1[rp] = idx32[gb + 1];
            i2[rp] = idx32[gb + 2];
        }
        bf16x8 a[4], b[4], c[4];
        #pragma unroll
        for (int rp = 0; rp < 4; ++rp)
            a[rp] = *(const bf16x8*)(Qt + QB0 + (size_t)i0[rp] * 256 + l31 * 8);
        #pragma unroll
        for (int rp = 0; rp < 4; ++rp)
            b[rp] = *(const bf16x8*)(Qt + QB1 + (size_t)i1[rp] * 256 + l31 * 8);
        #pragma unroll
        for (int rp = 0; rp < 4; ++rp)
            c[rp] = *(const bf16x8*)(Qt + QB2 + (size_t)i2[rp] * 256 + l31 * 8);
        #pragma unroll
        for (int rp = 0; rp < 4; ++rp) {
            bf16x8 o;
            #pragma unroll
            for (int j = 0; j < 8; ++j)
                o[j] = (bf16)fmaxf((float)a[rp][j] + (float)b[rp][j] + (float)c[rp][j], 0.f);
            const int r    = wave * 8 + rp * 2 + half;   // row in [0,32)
            const int mt   = r >> 4;
            const int l15r = r & 15;
            *(bf16x8*)(&sH2[((mt * 8 + ksw) * 64 + quadw * 16 + (l15r ^ ksw)) * 8]) = o;
        }
    }
    __syncthreads();

    const f32x4 zero4 = {0.f, 0.f, 0.f, 0.f};

    // Stage C: h3 = relu(h2 Wfc1^T + bfc1), waves split N(e) as wave*4+nt.
    f32x4 acc3[2][4];
    #pragma unroll
    for (int i = 0; i < 2; ++i)
        #pragma unroll
        for (int j = 0; j < 4; ++j) acc3[i][j] = zero4;
    #pragma unroll
    for (int ks = 0; ks < 8; ++ks) {
        bf16x8 af[2], bfr[4];
        #pragma unroll
        for (int mt = 0; mt < 2; ++mt)
            af[mt] = *(const bf16x8*)(&sH2[((mt * 8 + ks) * 64 + quad * 16 + (l15 ^ ks)) * 8]);
        #pragma unroll
        for (int nt = 0; nt < 4; ++nt)
            bfr[nt] = *(const bf16x8*)(wf + ((size_t)((wave * 4 + nt) * 8 + ks) * 64 + lane) * 8);
        #pragma unroll
        for (int mt = 0; mt < 2; ++mt)
            #pragma unroll
            for (int nt = 0; nt < 4; ++nt)
                acc3[mt][nt] = mfma16(af[mt], bfr[nt], acc3[mt][nt]);
    }

    // Stage D: per-wave partial into sPart, then one reduction pass.
    float wv[4], bc[4];
    #pragma unroll
    for (int nt = 0; nt < 4; ++nt) {
        int e = (wave * 4 + nt) * 16 + l15;
        wv[nt] = (float)wfc2[e];
        bc[nt] = fbc1[e];
    }
    #pragma unroll
    for (int mt = 0; mt < 2; ++mt)
        #pragma unroll
        for (int r = 0; r < 4; ++r) {
            float p = 0.f;
            #pragma unroll
            for (int nt = 0; nt < 4; ++nt)
                p += fmaxf(acc3[mt][nt][r] + bc[nt], 0.f) * wv[nt];
            p += __shfl_xor(p, 1, 64);
            p += __shfl_xor(p, 2, 64);
            p += __shfl_xor(p, 4, 64);
            p += __shfl_xor(p, 8, 64);
            if (l15 == 0) sPart[wave][mt * 16 + quad * 4 + r] = p;
        }
    __syncthreads();

    if (tid < BT) {
        float v = sPart[0][tid] + sPart[1][tid] + sPart[2][tid] + sPart[3][tid] + bfc2v;
        v = fmaxf(v, 0.f);
        if (fp32out) ((float*)out)[bbase + tid] = v;
        else         ((bf16*)out)[bbase + tid] = (bf16)v;
    }
}

extern "C" void kernel_launch(void* const* d_in, const int* in_sizes, int n_in,
                              void* d_out, int out_size, void* d_ws, size_t ws_size,
                              hipStream_t stream) {
    char* ws = (char*)d_ws;
    bf16*  wsb   = (bf16*)ws;
    float* wsf   = (float*)(ws + OFF_FLOAT);
    int*   flagp = (int*)(ws + OFF_FLAG);
    int*   idx32 = (int*)(ws + OFF_IDX);
    bf16*  Qt    = (bf16*)(ws + OFF_Q);

    hipLaunchKernelGGL(convert_all, dim3(1009), dim3(256), 0, stream,
                       d_in[1], d_in[2], d_in[3], d_in[4], d_in[5], d_in[6],
                       d_in[7], d_in[8], d_in[9], d_in[10], d_in[11], d_in[0],
                       wsb, wsf, flagp, idx32);

    hipLaunchKernelGGL(build_q, dim3(391), dim3(256), 0, stream, wsb, wsf, Qt);

    const int B = 131072;
    hipLaunchKernelGGL(costco_main, dim3(B / BT), dim3(256), 0, stream,
                       wsb, Qt, wsf, flagp, idx32, d_out);
}

// Round 8
// 120.458 us; speedup vs baseline: 1.0704x; 1.0106x over previous
//
#include <hip/hip_runtime.h>

typedef __bf16 bf16;
typedef __bf16 bf16x4 __attribute__((ext_vector_type(4)));
typedef __bf16 bf16x8 __attribute__((ext_vector_type(8)));
typedef float  f32x4  __attribute__((ext_vector_type(4)));
typedef unsigned int uint32;

#define BT 64

// ---- bf16 workspace layout (element offsets) ----
// All build_q operands stored in MFMA-fragment order:
//   frag(ee,kk,NKS): (((ee>>4)*NKS + (kk>>5))*64 + ((kk>>3)&3)*16 + (ee&15))*8 + (kk&7)
// EF*: emb tables, 16-row tiles (2048 elems/tile), padded to tile count.
#define N_EF0 (22*2048)
#define N_EF1 (365*2048)
#define N_EF2 (4*2048)
#define O_EF0 0
#define O_EF1 (O_EF0+N_EF0)      // 45056
#define O_EF2 (O_EF1+N_EF1)      // 792576
#define O_W1F (O_EF2+N_EF2)      // 800768  w1 fragment order (NKS=4)
#define O_W2F (O_W1F+32768)      // 833536  w2 per-mode fragment order [m][dt][ks][lane][8]
#define O_F1  (O_W2F+196608)     // 1030144 wfc1 fragment order (NKS=8)
#define O_F2  (O_F1+65536)       // 1095680 wfc2
#define N_TOT (O_F2+256)         // 1095936 bf16

#define BYTES_BF16 ((size_t)N_TOT*2)
#define OFF_FLOAT  BYTES_BF16              // f32: b1(256) b2(256) bfc1(256) bfc2(1)
#define OFF_FLAG   (OFF_FLOAT + 772*4)
#define OFF_IDX    (OFF_FLAG + 16)         // int32 idx (131072*3)
#define N_IDX      (131072*3)
#define OFF_Q      (OFF_IDX + (size_t)N_IDX*4)

// Q tables (bf16): Q_m[i][d], 6228 rows total -> 3.19 MB (L2-resident)
// b2 is folded into Q0 at build time.
#define QB0 0
#define QB1 (339*256)
#define QB2 (QB1 + 5825*256)

static __device__ __forceinline__ f32x4 mfma16(bf16x8 a, bf16x8 b, f32x4 c) {
    return __builtin_amdgcn_mfma_f32_16x16x32_bf16(a, b, c, 0, 0, 0);
}

// ---- prep. Blocks: [0,256) idx; 256 biases+flag+wfc2; [257,648) emb tiles;
// [648,664) w1 tiles; [664,680) wfc1 tiles; [680,696) w2 d-tiles.
// Every fragment table is built through LDS: coalesced source reads, LDS
// scatter (contiguous bf16x8 per thread), LINEAR uint4 global write-out.
// Zero scattered global writes anywhere.
__global__ __launch_bounds__(256)
void convert_all(const void* __restrict__ e0, const void* __restrict__ e1,
                 const void* __restrict__ e2, const void* __restrict__ w1r,
                 const void* __restrict__ b1r, const void* __restrict__ w2r,
                 const void* __restrict__ b2r, const void* __restrict__ f1r,
                 const void* __restrict__ fc1br, const void* __restrict__ f2r,
                 const void* __restrict__ fc2br, const void* __restrict__ idxr,
                 bf16* __restrict__ wsb, float* __restrict__ wsf,
                 int* __restrict__ flagp, int* __restrict__ idx32)
{
    __shared__ alignas(16) bf16 sT[12288];
    __shared__ int sF;
    const int tid = threadIdx.x;
    const int bid = blockIdx.x;
    if (tid == 0) sF = 0;
    __syncthreads();

    if (bid < 256) {
        // i64 probe: int64 index buffers (values < 2^31) have all-zero odd words
        if (((const uint32*)idxr)[tid * 2 + 1] != 0) atomicOr(&sF, 1);
        __syncthreads();
        const bool i64 = (sF == 0);
        #pragma unroll
        for (int it = 0; it < 6; ++it) {
            int k = bid * 1536 + it * 256 + tid;
            if (k < N_IDX) {
                long long v = i64 ? ((const long long*)idxr)[k]
                                  : (long long)((const int*)idxr)[k];
                int m = k - (k / 3) * 3;
                long long dim = (m == 0 ? 339 : (m == 1 ? 5825 : 64));
                v = v < 0 ? 0 : (v >= dim ? dim - 1 : v);
                idx32[k] = (int)v;
            }
        }
        return;
    }

    // fp32 probe: low 16 bits of word as bf16 with exp>126 impossible for |w1|<=0.37
    if (tid < 64) {
        uint32 e = (((const uint32*)w1r)[tid] >> 7) & 0xffu;
        if (e > 126u) atomicOr(&sF, 1);
    }
    __syncthreads();
    const bool fp32 = (sF != 0);

    if (bid == 256) {
        if (tid == 0) *flagp = fp32 ? 1 : 0;
        #pragma unroll
        for (int it = 0; it < 4; ++it) {
            int j = it * 256 + tid;
            if (j < 769) {
                const void* src; int off;
                if (j < 256)      { src = b1r;   off = j; }
                else if (j < 512) { src = b2r;   off = j - 256; }
                else if (j < 768) { src = fc1br; off = j - 512; }
                else              { src = fc2br; off = 0; }
                wsf[j] = fp32 ? ((const float*)src)[off] : (float)((const bf16*)src)[off];
            }
        }
        // wfc2 straight copy
        wsb[O_F2 + tid] = fp32 ? (bf16)((const float*)f2r)[tid]
                               : ((const bf16*)f2r)[tid];
    } else if (bid < 664) {
        // 16-row x 128-col fragment tile (emb or w1), NKS=4. 2048 elems.
        const int t = bid - 257;
        const void* src; int dim, tile, base;
        if (t < 22)       { src = e0;  dim = 339;  tile = t;       base = O_EF0; }
        else if (t < 387) { src = e1;  dim = 5825; tile = t - 22;  base = O_EF1; }
        else if (t < 391) { src = e2;  dim = 64;   tile = t - 387; base = O_EF2; }
        else              { src = w1r; dim = 256;  tile = t - 391; base = O_W1F; }
        const int g  = tid * 8;
        const int rl = g >> 7;            // local row 0..15
        const int kk = g & 127;
        int r = tile * 16 + rl; if (r >= dim) r = dim - 1;   // clamp pad rows
        bf16x8 v;
        if (fp32) {
            const float* s = (const float*)src + (size_t)r * 128 + kk;
            float4 A = *(const float4*)s, B = *(const float4*)(s + 4);
            v[0]=(bf16)A.x; v[1]=(bf16)A.y; v[2]=(bf16)A.z; v[3]=(bf16)A.w;
            v[4]=(bf16)B.x; v[5]=(bf16)B.y; v[6]=(bf16)B.z; v[7]=(bf16)B.w;
        } else {
            v = *(const bf16x8*)((const bf16*)src + (size_t)r * 128 + kk);
        }
        *(bf16x8*)(&sT[((kk >> 5) * 64 + ((kk >> 3) & 3) * 16 + rl) * 8]) = v;
        __syncthreads();
        *(uint4*)(wsb + base + tile * 2048 + tid * 8) = *(const uint4*)(&sT[tid * 8]);
    } else if (bid < 680) {
        // wfc1 tile et: 16 rows x 256 cols, NKS=8 -> 4096 elems.
        const int et = bid - 664;
        #pragma unroll
        for (int it = 0; it < 2; ++it) {
            const int g  = it * 2048 + tid * 8;
            const int rl = g >> 8;        // 0..15
            const int kk = g & 255;
            const size_t soff = (size_t)(et * 16 + rl) * 256 + kk;
            bf16x8 v;
            if (fp32) {
                const float* s = (const float*)f1r + soff;
                float4 A = *(const float4*)s, B = *(const float4*)(s + 4);
                v[0]=(bf16)A.x; v[1]=(bf16)A.y; v[2]=(bf16)A.z; v[3]=(bf16)A.w;
                v[4]=(bf16)B.x; v[5]=(bf16)B.y; v[6]=(bf16)B.z; v[7]=(bf16)B.w;
            } else {
                v = *(const bf16x8*)((const bf16*)f1r + soff);
            }
            *(bf16x8*)(&sT[((kk >> 5) * 64 + ((kk >> 3) & 3) * 16 + rl) * 8]) = v;
        }
        __syncthreads();
        #pragma unroll
        for (int it = 0; it < 2; ++it)
            *(uint4*)(wsb + O_F1 + et * 4096 + it * 2048 + tid * 8) =
                *(const uint4*)(&sT[it * 2048 + tid * 8]);
    } else {
        // w2 d-tile dt: d in [dt*16,(dt+1)*16). 12288 source elems (3 modes).
        const int dt = bid - 680;
        #pragma unroll
        for (int it = 0; it < 12; ++it) {
            unsigned g = it * 1024u + tid * 4u;
            unsigned goff = dt * 12288u + g;
            bf16 v4[4];
            if (fp32) {
                float4 t4 = *(const float4*)((const float*)w2r + goff);
                v4[0]=(bf16)t4.x; v4[1]=(bf16)t4.y; v4[2]=(bf16)t4.z; v4[3]=(bf16)t4.w;
            } else {
                bf16x4 t4 = *(const bf16x4*)((const bf16*)w2r + goff);
                v4[0]=t4[0]; v4[1]=t4[1]; v4[2]=t4[2]; v4[3]=t4[3];
            }
            unsigned dloc = g / 768u, rem = g - dloc * 768u;
            #pragma unroll
            for (int q2 = 0; q2 < 4; ++q2) {
                unsigned rr = rem + q2;
                unsigned c = rr / 3u, mm = rr - c * 3u;
                unsigned slot = mm * 4096u
                              + ((c >> 5) * 64u + ((c >> 3) & 3u) * 16u + dloc) * 8u
                              + (c & 7u);
                sT[slot] = v4[q2];
            }
        }
        __syncthreads();
        #pragma unroll
        for (int it = 0; it < 6; ++it) {
            unsigned mm = it >> 1, h = it & 1;
            *(uint4*)(wsb + O_W2F + mm * 65536 + dt * 4096 + h * 2048 + tid * 8) =
                *(const uint4*)(&sT[mm * 4096 + h * 2048 + tid * 8]);
        }
    }
}

// ---- build Q tables: Q_m[i][d] = sum_c relu(<emb_m[i],w1[c]>+b1[c]) * w2[d][c][m]
// One 16-row tile per block -> 391 blocks. All global loads lane-linear.
// b2[d] folded into Q0 (mode 0). (R4-verified structure, byte-identical)
__global__ __launch_bounds__(256)
void build_q(const bf16* __restrict__ wsb, const float* __restrict__ wsf,
             bf16* __restrict__ Qt)
{
    __shared__ alignas(16) bf16 sPE[4096];

    const int tid  = threadIdx.x;
    const int wave = tid >> 6;
    const int lane = tid & 63;
    const int quad = lane >> 4;
    const int l15  = lane & 15;
    const int bid  = blockIdx.x;

    int m, tile, dim, efBase, qBase;
    if (bid < 22)       { m = 0; tile = bid;       dim = 339;  efBase = O_EF0; qBase = QB0; }
    else if (bid < 387) { m = 1; tile = bid - 22;  dim = 5825; efBase = O_EF1; qBase = QB1; }
    else                { m = 2; tile = bid - 387; dim = 64;   efBase = O_EF2; qBase = QB2; }
    const int row0 = tile * 16;

    const bf16* w1f = wsb + O_W1F;
    const bf16* w2f = wsb + O_W2F + m * 65536;
    const float* fb1 = wsf;
    const float* fb2 = wsf + 256;
    const f32x4 zero4 = {0.f, 0.f, 0.f, 0.f};

    // emb B-fragments for this tile (shared across all mt)
    bf16x8 be[4];
    #pragma unroll
    for (int ks = 0; ks < 4; ++ks)
        be[ks] = *(const bf16x8*)(wsb + efBase + (size_t)((tile * 4 + ks) * 64 + lane) * 8);

    // Stage PE: H[c][row] = relu(w1.emb^T + b1); write into stage-Q A-fragment layout.
    #pragma unroll
    for (int mtl = 0; mtl < 4; ++mtl) {
        int mt = wave * 4 + mtl;
        f32x4 acc = zero4;
        #pragma unroll
        for (int ks = 0; ks < 4; ++ks) {
            bf16x8 aw = *(const bf16x8*)(w1f + ((mt * 4 + ks) * 64 + lane) * 8);
            acc = mfma16(aw, be[ks], acc);
        }
        const float4 bv = *(const float4*)(fb1 + mt * 16 + quad * 4);
        bf16x4 hv;
        hv[0] = (bf16)fmaxf(acc[0] + bv.x, 0.f);
        hv[1] = (bf16)fmaxf(acc[1] + bv.y, 0.f);
        hv[2] = (bf16)fmaxf(acc[2] + bv.z, 0.f);
        hv[3] = (bf16)fmaxf(acc[3] + bv.w, 0.f);
        // element (row=l15, c=mt*16+quad*4+r) -> A-frag (ks=c>>5, quadq=(c>>3)&3, j=c&7)
        int ksq   = mt >> 1;
        int quadq = ((mt & 1) << 1) | (quad >> 1);
        int j0    = (quad & 1) * 4;
        *(bf16x4*)(&sPE[(ksq * 64 + quadq * 16 + l15) * 8 + j0]) = hv;
    }
    __syncthreads();

    // Stage Q: A = H (16 rows), B = W2F d-tiles (wave*4+nt). No relu.
    f32x4 acc2[4];
    #pragma unroll
    for (int nt = 0; nt < 4; ++nt) acc2[nt] = zero4;
    #pragma unroll
    for (int ks = 0; ks < 8; ++ks) {
        bf16x8 af = *(const bf16x8*)(&sPE[(ks * 64 + lane) * 8]);
        #pragma unroll
        for (int nt = 0; nt < 4; ++nt) {
            bf16x8 bw = *(const bf16x8*)(w2f + (size_t)(((wave * 4 + nt) * 8 + ks) * 64 + lane) * 8);
            acc2[nt] = mfma16(af, bw, acc2[nt]);
        }
    }
    #pragma unroll
    for (int nt = 0; nt < 4; ++nt) {
        int d = (wave * 4 + nt) * 16 + l15;
        const float addb = (m == 0) ? fb2[d] : 0.f;   // fold b2 into Q0
        #pragma unroll
        for (int r = 0; r < 4; ++r) {
            int rl = quad * 4 + r;
            if (row0 + rl < dim)
                Qt[qBase + (size_t)(row0 + rl) * 256 + d] = (bf16)(acc2[nt][r] + addb);
        }
    }
}

// ---- main: h2 = relu(Q0'[i0]+Q1[i1]+Q2[i2]); h3 = relu(h2 Wfc1^T + bfc1);
// ---- out = relu(h3.wfc2 + bfc2). BT=64, 4 blocks/CU. (R4-verified structure,
// byte-identical — best measured config: 117.8us total)
__global__ __launch_bounds__(256, 4)
void costco_main(const bf16* __restrict__ wsb, const bf16* __restrict__ Qt,
                 const float* __restrict__ wsf, const int* __restrict__ flagp,
                 const int* __restrict__ idx32, void* __restrict__ out)
{
    __shared__ alignas(16) bf16 sH2[BT * 256];
    __shared__ float sPart[4][BT];

    const bf16* wf   = wsb + O_F1;   // fragment-ordered wfc1
    const bf16* wfc2 = wsb + O_F2;
    const float* fbc1 = wsf + 512;
    const float  bfc2v = wsf[768];
    const int fp32out = *flagp;

    const int tid  = threadIdx.x;
    const int wave = tid >> 6;
    const int lane = tid & 63;
    const int quad = lane >> 4;
    const int l15  = lane & 15;
    const int bbase = blockIdx.x * BT;

    // ---- gather: half-wave per row, idx loaded straight to registers ----
    {
        const int half  = lane >> 5;
        const int l31   = lane & 31;
        const int ksw   = l31 >> 2;
        const int quadw = l31 & 3;
        int i0[8], i1[8], i2[8];
        #pragma unroll
        for (int rp = 0; rp < 8; ++rp) {
            const int gb = (bbase + wave * 16 + rp * 2 + half) * 3;
            i0[rp] = idx32[gb];
            i1[rp] = idx32[gb + 1];
            i2[rp] = idx32[gb + 2];
        }
        #pragma unroll
        for (int rp = 0; rp < 8; ++rp) {
            bf16x8 a = *(const bf16x8*)(Qt + QB0 + (size_t)i0[rp] * 256 + l31 * 8);
            bf16x8 b = *(const bf16x8*)(Qt + QB1 + (size_t)i1[rp] * 256 + l31 * 8);
            bf16x8 c = *(const bf16x8*)(Qt + QB2 + (size_t)i2[rp] * 256 + l31 * 8);
            bf16x8 o;
            #pragma unroll
            for (int j = 0; j < 8; ++j)
                o[j] = (bf16)fmaxf((float)a[j] + (float)b[j] + (float)c[j], 0.f);
            const int l15r = rp * 2 + half;
            *(bf16x8*)(&sH2[((wave * 8 + ksw) * 64 + quadw * 16 + (l15r ^ ksw)) * 8]) = o;
        }
    }

    // hoist ks=0 wfc1 B-fragments above the barrier (L2 latency hides in drain)
    bf16x8 bfr0[4];
    #pragma unroll
    for (int nt = 0; nt < 4; ++nt)
        bfr0[nt] = *(const bf16x8*)(wf + ((size_t)((wave * 4 + nt) * 8) * 64 + lane) * 8);

    __syncthreads();

    const f32x4 zero4 = {0.f, 0.f, 0.f, 0.f};

    // Stage C: h3 = relu(h2 Wfc1^T + bfc1), waves split N(e).
    f32x4 acc3[4][4];
    #pragma unroll
    for (int i = 0; i < 4; ++i)
        #pragma unroll
        for (int j = 0; j < 4; ++j) acc3[i][j] = zero4;
    #pragma unroll
    for (int ks = 0; ks < 8; ++ks) {
        bf16x8 af[4], bfr[4];
        #pragma unroll
        for (int mt = 0; mt < 4; ++mt)
            af[mt] = *(const bf16x8*)(&sH2[((mt * 8 + ks) * 64 + quad * 16 + (l15 ^ ks)) * 8]);
        #pragma unroll
        for (int nt = 0; nt < 4; ++nt)
            bfr[nt] = (ks == 0) ? bfr0[nt]
                    : *(const bf16x8*)(wf + ((size_t)((wave * 4 + nt) * 8 + ks) * 64 + lane) * 8);
        #pragma unroll
        for (int mt = 0; mt < 4; ++mt)
            #pragma unroll
            for (int nt = 0; nt < 4; ++nt)
                acc3[mt][nt] = mfma16(af[mt], bfr[nt], acc3[mt][nt]);
    }

    // Stage D: per-wave partial into sPart, then one reduction pass.
    float wv[4], bc[4];
    #pragma unroll
    for (int nt = 0; nt < 4; ++nt) {
        int e = wave * 64 + nt * 16 + l15;
        wv[nt] = (float)wfc2[e];
        bc[nt] = fbc1[e];
    }
    #pragma unroll
    for (int mt = 0; mt < 4; ++mt)
        #pragma unroll
        for (int r = 0; r < 4; ++r) {
            float p = 0.f;
            #pragma unroll
            for (int nt = 0; nt < 4; ++nt)
                p += fmaxf(acc3[mt][nt][r] + bc[nt], 0.f) * wv[nt];
            p += __shfl_xor(p, 1, 64);
            p += __shfl_xor(p, 2, 64);
            p += __shfl_xor(p, 4, 64);
            p += __shfl_xor(p, 8, 64);
            if (l15 == 0) sPart[wave][mt * 16 + quad * 4 + r] = p;
        }
    __syncthreads();

    if (tid < BT) {
        float v = sPart[0][tid] + sPart[1][tid] + sPart[2][tid] + sPart[3][tid] + bfc2v;
        v = fmaxf(v, 0.f);
        if (fp32out) ((float*)out)[bbase + tid] = v;
        else         ((bf16*)out)[bbase + tid] = (bf16)v;
    }
}

extern "C" void kernel_launch(void* const* d_in, const int* in_sizes, int n_in,
                              void* d_out, int out_size, void* d_ws, size_t ws_size,
                              hipStream_t stream) {
    char* ws = (char*)d_ws;
    bf16*  wsb   = (bf16*)ws;
    float* wsf   = (float*)(ws + OFF_FLOAT);
    int*   flagp = (int*)(ws + OFF_FLAG);
    int*   idx32 = (int*)(ws + OFF_IDX);
    bf16*  Qt    = (bf16*)(ws + OFF_Q);

    hipLaunchKernelGGL(convert_all, dim3(696), dim3(256), 0, stream,
                       d_in[1], d_in[2], d_in[3], d_in[4], d_in[5], d_in[6],
                       d_in[7], d_in[8], d_in[9], d_in[10], d_in[11], d_in[0],
                       wsb, wsf, flagp, idx32);

    hipLaunchKernelGGL(build_q, dim3(391), dim3(256), 0, stream, wsb, wsf, Qt);

    const int B = 131072;
    hipLaunchKernelGGL(costco_main, dim3(B / BT), dim3(256), 0, stream,
                       wsb, Qt, wsf, flagp, idx32, d_out);
}

// Round 9
// 117.504 us; speedup vs baseline: 1.0973x; 1.0251x over previous
//
#include <hip/hip_runtime.h>

typedef __bf16 bf16;
typedef __bf16 bf16x4 __attribute__((ext_vector_type(4)));
typedef __bf16 bf16x8 __attribute__((ext_vector_type(8)));
typedef float  f32x4  __attribute__((ext_vector_type(4)));
typedef unsigned int uint32;

#define BT 64

// ---- bf16 workspace layout (element offsets) ----
// All build_q operands stored in MFMA-fragment order:
//   frag(ee,kk,NKS): (((ee>>4)*NKS + (kk>>5))*64 + ((kk>>3)&3)*16 + (ee&15))*8 + (kk&7)
// EF*: emb tables, 16-row tiles (2048 elems/tile), padded to tile count.
#define N_EF0 (22*2048)
#define N_EF1 (365*2048)
#define N_EF2 (4*2048)
#define O_EF0 0
#define O_EF1 (O_EF0+N_EF0)      // 45056
#define O_EF2 (O_EF1+N_EF1)      // 792576
#define O_W1F (O_EF2+N_EF2)      // 800768  w1 fragment order (NKS=4)
#define O_W2F (O_W1F+32768)      // 833536  w2 per-mode fragment order [m][dt][ks][lane][8]
#define O_F1  (O_W2F+196608)     // 1030144 wfc1 fragment order (NKS=8)
#define O_F2  (O_F1+65536)       // 1095680 wfc2
#define N_TOT (O_F2+256)         // 1095936 bf16

#define BYTES_BF16 ((size_t)N_TOT*2)
#define OFF_FLOAT  BYTES_BF16              // f32: b1(256) b2(256) bfc1(256) bfc2(1)
#define OFF_FLAG   (OFF_FLOAT + 772*4)
#define OFF_IDX    (OFF_FLAG + 16)         // int32 idx (131072*3)
#define N_IDX      (131072*3)
#define OFF_Q      (OFF_IDX + (size_t)N_IDX*4)

// Q tables (bf16): Q_m[i][d], 6228 rows total -> 3.19 MB (L2-resident)
// b2 is folded into Q0 at build time.
#define QB0 0
#define QB1 (339*256)
#define QB2 (QB1 + 5825*256)

static __device__ __forceinline__ f32x4 mfma16(bf16x8 a, bf16x8 b, f32x4 c) {
    return __builtin_amdgcn_mfma_f32_16x16x32_bf16(a, b, c, 0, 0, 0);
}

static __device__ __forceinline__ unsigned frag_off(unsigned ee, unsigned kk, unsigned nks) {
    return (((ee >> 4) * nks + (kk >> 5)) * 64u + ((kk >> 3) & 3u) * 16u + (ee & 15u)) * 8u
           + (kk & 7u);
}

// ---- normalization. Block ranges: [0,256) idx; [256,768) fragment-copy;
// [768,1008) w2 fragment-transpose; 1008 biases+flag. (R4-verified structure)
__global__ __launch_bounds__(256)
void convert_all(const void* __restrict__ e0, const void* __restrict__ e1,
                 const void* __restrict__ e2, const void* __restrict__ w1r,
                 const void* __restrict__ b1r, const void* __restrict__ w2r,
                 const void* __restrict__ b2r, const void* __restrict__ f1r,
                 const void* __restrict__ fc1br, const void* __restrict__ f2r,
                 const void* __restrict__ fc2br, const void* __restrict__ idxr,
                 bf16* __restrict__ wsb, float* __restrict__ wsf,
                 int* __restrict__ flagp, int* __restrict__ idx32)
{
    __shared__ int sF;
    const int tid = threadIdx.x;
    const int bid = blockIdx.x;
    if (tid == 0) sF = 0;
    __syncthreads();

    if (bid < 256) {
        // i64 probe: int64 index buffers (values < 2^31) have all-zero odd words
        if (((const uint32*)idxr)[tid * 2 + 1] != 0) atomicOr(&sF, 1);
        __syncthreads();
        const bool i64 = (sF == 0);
        #pragma unroll
        for (int it = 0; it < 6; ++it) {
            int k = bid * 1536 + it * 256 + tid;
            if (k < N_IDX) {
                long long v = i64 ? ((const long long*)idxr)[k]
                                  : (long long)((const int*)idxr)[k];
                int m = k - (k / 3) * 3;
                long long dim = (m == 0 ? 339 : (m == 1 ? 5825 : 64));
                v = v < 0 ? 0 : (v >= dim ? dim - 1 : v);
                idx32[k] = (int)v;
            }
        }
        return;
    }

    // fp32 probe: low 16 bits of word as bf16 with exp>126 impossible for |w1|<=0.37
    if (tid < 64) {
        uint32 e = (((const uint32*)w1r)[tid] >> 7) & 0xffu;
        if (e > 126u) atomicOr(&sF, 1);
    }
    __syncthreads();
    const bool fp32 = (sF != 0);

    if (bid < 768) {
        // fragment-copy, source-linear in 4-elt chunks (all region sizes %4==0).
        // cum: e0 43392 | e1 788992 | e2 797184 | w1 829952 | f1 895488 | f2 895744
        const unsigned n4 = 895744u / 4u;
        for (unsigned u = (bid - 256) * 256u + tid; u < n4; u += 512u * 256u) {
            unsigned e = u * 4;
            const void* src; unsigned off, dst;
            if (e < 829952u) {   // emb/w1: fragment NKS=4
                unsigned base;
                if (e < 43392u)       { src = e0;  off = e;           base = O_EF0; }
                else if (e < 788992u) { src = e1;  off = e - 43392u;  base = O_EF1; }
                else if (e < 797184u) { src = e2;  off = e - 788992u; base = O_EF2; }
                else                  { src = w1r; off = e - 797184u; base = O_W1F; }
                dst = base + frag_off(off >> 7, off & 127u, 4u);
            } else if (e < 895488u) {  // wfc1: fragment NKS=8
                src = f1r; off = e - 829952u;
                dst = O_F1 + frag_off(off >> 8, off & 255u, 8u);
            } else {                   // wfc2 straight
                src = f2r; off = e - 895488u; dst = O_F2 + off;
            }
            if (fp32) {
                float4 v = *(const float4*)((const float*)src + off);
                bf16x4 o; o[0]=(bf16)v.x; o[1]=(bf16)v.y; o[2]=(bf16)v.z; o[3]=(bf16)v.w;
                *(bf16x4*)(wsb + dst) = o;
            } else {
                *(uint2*)(wsb + dst) = *(const uint2*)((const bf16*)src + off);
            }
        }
    } else if (bid < 1008) {
        // W2F[m][dt][ks][lane][j] = w2[d][c][m], d=dt*16+(lane&15), c=ks*32+(lane>>4)*8+j
        for (unsigned i = (bid - 768) * 256u + tid; i < 196608u; i += 240u * 256u) {
            unsigned m = i >> 16, r = i & 65535u;
            unsigned dt = r >> 12, ks = (r >> 9) & 7u, lane = (r >> 3) & 63u, j = r & 7u;
            unsigned d = dt * 16u + (lane & 15u);
            unsigned c = ks * 32u + (lane >> 4) * 8u + j;
            unsigned off = d * 768u + c * 3u + m;
            wsb[O_W2F + i] = fp32 ? (bf16)((const float*)w2r)[off] : ((const bf16*)w2r)[off];
        }
    } else {
        if (tid == 0) *flagp = fp32 ? 1 : 0;
        #pragma unroll
        for (int it = 0; it < 4; ++it) {
            int j = it * 256 + tid;
            if (j < 769) {
                const void* src; int off;
                if (j < 256)      { src = b1r;   off = j; }
                else if (j < 512) { src = b2r;   off = j - 256; }
                else if (j < 768) { src = fc1br; off = j - 512; }
                else              { src = fc2br; off = 0; }
                wsf[j] = fp32 ? ((const float*)src)[off] : (float)((const bf16*)src)[off];
            }
        }
    }
}

// ---- build Q tables: Q_m[i][d] = sum_c relu(<emb_m[i],w1[c]>+b1[c]) * w2[d][c][m]
// One 16-row tile per block -> 391 blocks. All global loads lane-linear.
// b2[d] folded into Q0 (mode 0). (R4-verified structure)
__global__ __launch_bounds__(256)
void build_q(const bf16* __restrict__ wsb, const float* __restrict__ wsf,
             bf16* __restrict__ Qt)
{
    __shared__ alignas(16) bf16 sPE[4096];

    const int tid  = threadIdx.x;
    const int wave = tid >> 6;
    const int lane = tid & 63;
    const int quad = lane >> 4;
    const int l15  = lane & 15;
    const int bid  = blockIdx.x;

    int m, tile, dim, efBase, qBase;
    if (bid < 22)       { m = 0; tile = bid;       dim = 339;  efBase = O_EF0; qBase = QB0; }
    else if (bid < 387) { m = 1; tile = bid - 22;  dim = 5825; efBase = O_EF1; qBase = QB1; }
    else                { m = 2; tile = bid - 387; dim = 64;   efBase = O_EF2; qBase = QB2; }
    const int row0 = tile * 16;

    const bf16* w1f = wsb + O_W1F;
    const bf16* w2f = wsb + O_W2F + m * 65536;
    const float* fb1 = wsf;
    const float* fb2 = wsf + 256;
    const f32x4 zero4 = {0.f, 0.f, 0.f, 0.f};

    // emb B-fragments for this tile (shared across all mt)
    bf16x8 be[4];
    #pragma unroll
    for (int ks = 0; ks < 4; ++ks)
        be[ks] = *(const bf16x8*)(wsb + efBase + (size_t)((tile * 4 + ks) * 64 + lane) * 8);

    // Stage PE: H[c][row] = relu(w1.emb^T + b1); write into stage-Q A-fragment layout.
    #pragma unroll
    for (int mtl = 0; mtl < 4; ++mtl) {
        int mt = wave * 4 + mtl;
        f32x4 acc = zero4;
        #pragma unroll
        for (int ks = 0; ks < 4; ++ks) {
            bf16x8 aw = *(const bf16x8*)(w1f + ((mt * 4 + ks) * 64 + lane) * 8);
            acc = mfma16(aw, be[ks], acc);
        }
        const float4 bv = *(const float4*)(fb1 + mt * 16 + quad * 4);
        bf16x4 hv;
        hv[0] = (bf16)fmaxf(acc[0] + bv.x, 0.f);
        hv[1] = (bf16)fmaxf(acc[1] + bv.y, 0.f);
        hv[2] = (bf16)fmaxf(acc[2] + bv.z, 0.f);
        hv[3] = (bf16)fmaxf(acc[3] + bv.w, 0.f);
        // element (row=l15, c=mt*16+quad*4+r) -> A-frag (ks=c>>5, quadq=(c>>3)&3, j=c&7)
        int ksq   = mt >> 1;
        int quadq = ((mt & 1) << 1) | (quad >> 1);
        int j0    = (quad & 1) * 4;
        *(bf16x4*)(&sPE[(ksq * 64 + quadq * 16 + l15) * 8 + j0]) = hv;
    }
    __syncthreads();

    // Stage Q: A = H (16 rows), B = W2F d-tiles (wave*4+nt). No relu.
    f32x4 acc2[4];
    #pragma unroll
    for (int nt = 0; nt < 4; ++nt) acc2[nt] = zero4;
    #pragma unroll
    for (int ks = 0; ks < 8; ++ks) {
        bf16x8 af = *(const bf16x8*)(&sPE[(ks * 64 + lane) * 8]);
        #pragma unroll
        for (int nt = 0; nt < 4; ++nt) {
            bf16x8 bw = *(const bf16x8*)(w2f + (size_t)(((wave * 4 + nt) * 8 + ks) * 64 + lane) * 8);
            acc2[nt] = mfma16(af, bw, acc2[nt]);
        }
    }
    #pragma unroll
    for (int nt = 0; nt < 4; ++nt) {
        int d = (wave * 4 + nt) * 16 + l15;
        const float addb = (m == 0) ? fb2[d] : 0.f;   // fold b2 into Q0
        #pragma unroll
        for (int r = 0; r < 4; ++r) {
            int rl = quad * 4 + r;
            if (row0 + rl < dim)
                Qt[qBase + (size_t)(row0 + rl) * 256 + d] = (bf16)(acc2[nt][r] + addb);
        }
    }
}

// ---- main: h2 = relu(Q0'[i0]+Q1[i1]+Q2[i2]); h3 = relu(h2 Wfc1^T + bfc1);
// ---- out = relu(h3.wfc2 + bfc2). BT=64, 4 blocks/CU. (R4-verified structure —
// best measured config: 117.8us total, reproduced twice)
__global__ __launch_bounds__(256, 4)
void costco_main(const bf16* __restrict__ wsb, const bf16* __restrict__ Qt,
                 const float* __restrict__ wsf, const int* __restrict__ flagp,
                 const int* __restrict__ idx32, void* __restrict__ out)
{
    __shared__ alignas(16) bf16 sH2[BT * 256];
    __shared__ float sPart[4][BT];

    const bf16* wf   = wsb + O_F1;   // fragment-ordered wfc1
    const bf16* wfc2 = wsb + O_F2;
    const float* fbc1 = wsf + 512;
    const float  bfc2v = wsf[768];
    const int fp32out = *flagp;

    const int tid  = threadIdx.x;
    const int wave = tid >> 6;
    const int lane = tid & 63;
    const int quad = lane >> 4;
    const int l15  = lane & 15;
    const int bbase = blockIdx.x * BT;

    // ---- gather: half-wave per row, idx loaded straight to registers ----
    {
        const int half  = lane >> 5;
        const int l31   = lane & 31;
        const int ksw   = l31 >> 2;
        const int quadw = l31 & 3;
        int i0[8], i1[8], i2[8];
        #pragma unroll
        for (int rp = 0; rp < 8; ++rp) {
            const int gb = (bbase + wave * 16 + rp * 2 + half) * 3;
            i0[rp] = idx32[gb];
            i1[rp] = idx32[gb + 1];
            i2[rp] = idx32[gb + 2];
        }
        #pragma unroll
        for (int rp = 0; rp < 8; ++rp) {
            bf16x8 a = *(const bf16x8*)(Qt + QB0 + (size_t)i0[rp] * 256 + l31 * 8);
            bf16x8 b = *(const bf16x8*)(Qt + QB1 + (size_t)i1[rp] * 256 + l31 * 8);
            bf16x8 c = *(const bf16x8*)(Qt + QB2 + (size_t)i2[rp] * 256 + l31 * 8);
            bf16x8 o;
            #pragma unroll
            for (int j = 0; j < 8; ++j)
                o[j] = (bf16)fmaxf((float)a[j] + (float)b[j] + (float)c[j], 0.f);
            const int l15r = rp * 2 + half;
            *(bf16x8*)(&sH2[((wave * 8 + ksw) * 64 + quadw * 16 + (l15r ^ ksw)) * 8]) = o;
        }
    }

    // hoist ks=0 wfc1 B-fragments above the barrier (L2 latency hides in drain)
    bf16x8 bfr0[4];
    #pragma unroll
    for (int nt = 0; nt < 4; ++nt)
        bfr0[nt] = *(const bf16x8*)(wf + ((size_t)((wave * 4 + nt) * 8) * 64 + lane) * 8);

    __syncthreads();

    const f32x4 zero4 = {0.f, 0.f, 0.f, 0.f};

    // Stage C: h3 = relu(h2 Wfc1^T + bfc1), waves split N(e).
    f32x4 acc3[4][4];
    #pragma unroll
    for (int i = 0; i < 4; ++i)
        #pragma unroll
        for (int j = 0; j < 4; ++j) acc3[i][j] = zero4;
    #pragma unroll
    for (int ks = 0; ks < 8; ++ks) {
        bf16x8 af[4], bfr[4];
        #pragma unroll
        for (int mt = 0; mt < 4; ++mt)
            af[mt] = *(const bf16x8*)(&sH2[((mt * 8 + ks) * 64 + quad * 16 + (l15 ^ ks)) * 8]);
        #pragma unroll
        for (int nt = 0; nt < 4; ++nt)
            bfr[nt] = (ks == 0) ? bfr0[nt]
                    : *(const bf16x8*)(wf + ((size_t)((wave * 4 + nt) * 8 + ks) * 64 + lane) * 8);
        #pragma unroll
        for (int mt = 0; mt < 4; ++mt)
            #pragma unroll
            for (int nt = 0; nt < 4; ++nt)
                acc3[mt][nt] = mfma16(af[mt], bfr[nt], acc3[mt][nt]);
    }

    // Stage D: per-wave partial into sPart, then one reduction pass.
    float wv[4], bc[4];
    #pragma unroll
    for (int nt = 0; nt < 4; ++nt) {
        int e = wave * 64 + nt * 16 + l15;
        wv[nt] = (float)wfc2[e];
        bc[nt] = fbc1[e];
    }
    #pragma unroll
    for (int mt = 0; mt < 4; ++mt)
        #pragma unroll
        for (int r = 0; r < 4; ++r) {
            float p = 0.f;
            #pragma unroll
            for (int nt = 0; nt < 4; ++nt)
                p += fmaxf(acc3[mt][nt][r] + bc[nt], 0.f) * wv[nt];
            p += __shfl_xor(p, 1, 64);
            p += __shfl_xor(p, 2, 64);
            p += __shfl_xor(p, 4, 64);
            p += __shfl_xor(p, 8, 64);
            if (l15 == 0) sPart[wave][mt * 16 + quad * 4 + r] = p;
        }
    __syncthreads();

    if (tid < BT) {
        float v = sPart[0][tid] + sPart[1][tid] + sPart[2][tid] + sPart[3][tid] + bfc2v;
        v = fmaxf(v, 0.f);
        if (fp32out) ((float*)out)[bbase + tid] = v;
        else         ((bf16*)out)[bbase + tid] = (bf16)v;
    }
}

extern "C" void kernel_launch(void* const* d_in, const int* in_sizes, int n_in,
                              void* d_out, int out_size, void* d_ws, size_t ws_size,
                              hipStream_t stream) {
    char* ws = (char*)d_ws;
    bf16*  wsb   = (bf16*)ws;
    float* wsf   = (float*)(ws + OFF_FLOAT);
    int*   flagp = (int*)(ws + OFF_FLAG);
    int*   idx32 = (int*)(ws + OFF_IDX);
    bf16*  Qt    = (bf16*)(ws + OFF_Q);

    hipLaunchKernelGGL(convert_all, dim3(1009), dim3(256), 0, stream,
                       d_in[1], d_in[2], d_in[3], d_in[4], d_in[5], d_in[6],
                       d_in[7], d_in[8], d_in[9], d_in[10], d_in[11], d_in[0],
                       wsb, wsf, flagp, idx32);

    hipLaunchKernelGGL(build_q, dim3(391), dim3(256), 0, stream, wsb, wsf, Qt);

    const int B = 131072;
    hipLaunchKernelGGL(costco_main, dim3(B / BT), dim3(256), 0, stream,
                       wsb, Qt, wsf, flagp, idx32, d_out);
}